// Round 6
// baseline (3163.985 us; speedup 1.0000x reference)
//
#include <hip/hip_runtime.h>
#include <stdint.h>
#include <stddef.h>

#define B_  64
#define S_  512
#define I_  512
#define H_  1024
#define G_  3072
#define NWG 64      // 32 col-strips x 2 batch-halves
#define CPW 32      // h-columns per wg

typedef short short8 __attribute__((ext_vector_type(8)));
typedef float f32x4  __attribute__((ext_vector_type(4)));
typedef unsigned short u16x4 __attribute__((ext_vector_type(4)));

__device__ __forceinline__ unsigned short f32_to_bf16(float f){
  unsigned u = __builtin_bit_cast(unsigned, f);
  u = (u + 0x7FFFu + ((u >> 16) & 1u)) >> 16;
  return (unsigned short)u;
}
__device__ __forceinline__ float bf16_to_f32(unsigned short s){
  unsigned u = ((unsigned)s) << 16;
  return __builtin_bit_cast(float, u);
}
__device__ __forceinline__ float sig_(float x){ return 1.0f/(1.0f + __expf(-x)); }
__device__ __forceinline__ float tanh_(float x){
  float ax = fabsf(x);
  float t = __expf(-2.0f*ax);
  float r = (1.0f - t)/(1.0f + t);
  return copysignf(r, x);
}

// coherent (cross-XCD visible) accesses: bypass caches to LLC via sc0 sc1
__device__ __forceinline__ short8 ldg16_coh(const unsigned short* p){
  short8 r;
  asm volatile("global_load_dwordx4 %0, %1, off sc0 sc1" : "=v"(r) : "v"(p) : "memory");
  return r;
}
__device__ __forceinline__ void stg8_coh(unsigned short* p, u16x4 v){
  asm volatile("global_store_dwordx2 %0, %1, off sc0 sc1" :: "v"(p), "v"(v) : "memory");
}
__device__ __forceinline__ void stg4_coh(unsigned* p, unsigned v){
  asm volatile("global_store_dword %0, %1, off sc0 sc1" :: "v"(p), "v"(v) : "memory");
}
__device__ __forceinline__ unsigned ldg4_coh_wait(const unsigned* p){
  unsigned r;
  asm volatile("global_load_dword %0, %1, off sc0 sc1\n\ts_waitcnt vmcnt(0)"
               : "=v"(r) : "v"(p) : "memory");
  return r;
}
__device__ __forceinline__ u16x4 ldg8(const unsigned short* p){
  u16x4 r;
  asm volatile("global_load_dwordx2 %0, %1, off" : "=v"(r) : "v"(p) : "memory");
  return r;
}

// ---------------- f32 -> bf16 cast ----------------
__global__ __launch_bounds__(256) void k_cvt4(const float* __restrict__ src,
                                              unsigned short* __restrict__ dst, int n4){
  int i = blockIdx.x*blockDim.x + threadIdx.x;
  int st = gridDim.x*blockDim.x;
  for (; i < n4; i += st){
    f32x4 v = *(const f32x4*)(src + (size_t)i*4);
    u16x4 o;
    o[0]=f32_to_bf16(v[0]); o[1]=f32_to_bf16(v[1]);
    o[2]=f32_to_bf16(v[2]); o[3]=f32_to_bf16(v[3]);
    *(u16x4*)(dst + (size_t)i*4) = o;
  }
}

// ---------------- column means of Whh -> CM[16][1024] -----------------------
__global__ __launch_bounds__(256) void k_cmean(const float* __restrict__ whh,
                                               unsigned short* __restrict__ CM){
  int k = blockIdx.x*256 + threadIdx.x;   // grid = 4 x 256 -> k in [0,1024)
  float s0 = 0.f, s1 = 0.f;
  for (int j = 0; j < 2048; ++j) s0 += whh[(size_t)j*H_ + k];
  for (int j = 2048; j < 3072; ++j) s1 += whh[(size_t)j*H_ + k];
  CM[k]      = f32_to_bf16(s0 * (1.0f/2048.0f));
  CM[H_ + k] = f32_to_bf16(s1 * (1.0f/1024.0f));
  for (int r = 2; r < 16; ++r) CM[(size_t)r*H_ + k] = 0;
}

// ---------------- ih = X @ Wih^T  (writes time-major: row' = s*64 + b) ------
__global__ __launch_bounds__(256, 2) void k_gemm_ih(
    const unsigned short* __restrict__ X,    // [32768][512]
    const unsigned short* __restrict__ W,    // [3072][512]
    unsigned short* __restrict__ IH)         // [512][64][3072]
{
  __shared__ __align__(16) short As[128*32];
  __shared__ __align__(16) short Bs[128*32];
  int bid = blockIdx.x;
  int mt = bid / 24, nt = bid % 24;
  int tid = threadIdx.x, lane = tid & 63, wid = tid >> 6;
  int vr = wid >> 1, vc = wid & 1;
  int r0s = tid >> 2, r1s = r0s + 64;
  int sc = (tid & 3) * 8;
  const unsigned short* xa0 = X + (size_t)(mt*128 + r0s)*512 + sc;
  const unsigned short* xa1 = X + (size_t)(mt*128 + r1s)*512 + sc;
  const unsigned short* wb0 = W + (size_t)(nt*128 + r0s)*512 + sc;
  const unsigned short* wb1 = W + (size_t)(nt*128 + r1s)*512 + sc;

  f32x4 acc[4][4];
  #pragma unroll
  for (int m=0;m<4;m++)
    #pragma unroll
    for (int n=0;n<4;n++) acc[m][n] = (f32x4){0.f,0.f,0.f,0.f};

  short8 ra0 = *(const short8*)xa0;
  short8 ra1 = *(const short8*)xa1;
  short8 rb0 = *(const short8*)wb0;
  short8 rb1 = *(const short8*)wb1;
  int ko = (lane >> 4) * 8;

  for (int kt = 0; kt < 16; ++kt){
    __syncthreads();
    *(short8*)&As[r0s*32 + sc] = ra0;
    *(short8*)&As[r1s*32 + sc] = ra1;
    *(short8*)&Bs[r0s*32 + sc] = rb0;
    *(short8*)&Bs[r1s*32 + sc] = rb1;
    __syncthreads();
    if (kt < 15){
      ra0 = *(const short8*)(xa0 + (kt+1)*32);
      ra1 = *(const short8*)(xa1 + (kt+1)*32);
      rb0 = *(const short8*)(wb0 + (kt+1)*32);
      rb1 = *(const short8*)(wb1 + (kt+1)*32);
    }
    short8 af[4], bfr[4];
    #pragma unroll
    for (int m=0;m<4;m++) af[m]  = *(const short8*)&As[(vr*64 + m*16 + (lane&15))*32 + ko];
    #pragma unroll
    for (int n=0;n<4;n++) bfr[n] = *(const short8*)&Bs[(vc*64 + n*16 + (lane&15))*32 + ko];
    #pragma unroll
    for (int m=0;m<4;m++)
      #pragma unroll
      for (int n=0;n<4;n++)
        acc[m][n] = __builtin_amdgcn_mfma_f32_16x16x32_bf16(af[m], bfr[n], acc[m][n], 0,0,0);
  }
  int row0 = mt*128 + vr*64, col0 = nt*128 + vc*64;
  int rl = (lane >> 4) * 4, cl = lane & 15;
  #pragma unroll
  for (int m=0;m<4;m++)
    #pragma unroll
    for (int n=0;n<4;n++)
      #pragma unroll
      for (int r=0;r<4;r++){
        int row = row0 + m*16 + rl + r;             // b*512 + s
        int rowT = ((row & 511) << 6) | (row >> 9); // s*64 + b
        IH[(size_t)rowT*G_ + (col0 + n*16 + cl)] = f32_to_bf16(acc[m][n][r]);
      }
}

// ---------------- row LayerNorm (ddof=1) over [0:2048) and [2048:3072) ------
__global__ __launch_bounds__(256) void k_ln(
    unsigned short* __restrict__ IH,
    const float* __restrict__ gih,
    const float* __restrict__ bih)
{
  __shared__ float red[4][4];
  int row = blockIdx.x, tid = threadIdx.x, lane = tid & 63, wid = tid >> 6;
  unsigned short* p = IH + (size_t)row * G_;
  float xv[3][4];
  #pragma unroll
  for (int q=0;q<3;q++){
    u16x4 v = *(const u16x4*)(p + (tid + q*256)*4);
    #pragma unroll
    for (int j=0;j<4;j++) xv[q][j] = bf16_to_f32(v[j]);
  }
  float s0=0, q0=0, s1=0, q1=0;
  #pragma unroll
  for (int q=0;q<2;q++)
    #pragma unroll
    for (int j=0;j<4;j++){ s0 += xv[q][j]; q0 += xv[q][j]*xv[q][j]; }
  #pragma unroll
  for (int j=0;j<4;j++){ s1 += xv[2][j]; q1 += xv[2][j]*xv[2][j]; }
  #pragma unroll
  for (int off=32; off>0; off>>=1){
    s0 += __shfl_down(s0, off, 64);
    q0 += __shfl_down(q0, off, 64);
    s1 += __shfl_down(s1, off, 64);
    q1 += __shfl_down(q1, off, 64);
  }
  if (lane == 0){ red[wid][0]=s0; red[wid][1]=q0; red[wid][2]=s1; red[wid][3]=q1; }
  __syncthreads();
  float S0 = red[0][0]+red[1][0]+red[2][0]+red[3][0];
  float Q0 = red[0][1]+red[1][1]+red[2][1]+red[3][1];
  float S1 = red[0][2]+red[1][2]+red[2][2]+red[3][2];
  float Q1 = red[0][3]+red[1][3]+red[2][3]+red[3][3];
  float m0 = S0 * (1.0f/2048.0f);
  float rs0 = rsqrtf(fmaxf((Q0 - S0*m0) * (1.0f/2047.0f), 1e-20f));
  float m1 = S1 * (1.0f/1024.0f);
  float rs1 = rsqrtf(fmaxf((Q1 - S1*m1) * (1.0f/1023.0f), 1e-20f));
  #pragma unroll
  for (int q=0;q<3;q++){
    int base = (tid + q*256)*4;
    u16x4 o;
    #pragma unroll
    for (int j=0;j<4;j++){
      int col = base + j;
      float y = (q<2) ? (xv[q][j]-m0)*rs0 : (xv[q][j]-m1)*rs1;
      o[j] = f32_to_bf16(gih[col]*y + bih[col]);
    }
    *(u16x4*)(p + base) = o;
  }
}

// ---------------- persistent GRU recurrence ---------------------------------
// 64 wgs = 32 col-strips x 2 independent batch-halves. Per wg: 32 cols, 32 rows.
// Flags: packed, FLAGS[p*32 + g] (4B stride; one 128B line per half).
__global__ __launch_bounds__(256, 1) void k_gru(
    const unsigned short* __restrict__ IH,   // [512][64][3072] bf16 post-LN
    const unsigned short* __restrict__ WHH,  // [3072][1024] bf16
    const unsigned short* __restrict__ CM,   // [16][1024] bf16
    unsigned short* __restrict__ HB,         // 2 x [64][1024] bf16 ping-pong
    const float* __restrict__ ghh,
    const float* __restrict__ bhh,
    const float* __restrict__ state,
    float* __restrict__ out,
    unsigned* __restrict__ FLAGS)
{
  __shared__ float PSUM[4][112][34];
  const int g = blockIdx.x & 31;        // col-strip
  const int p = blockIdx.x >> 5;        // batch-half
  const int tid = threadIdx.x;
  const int lane = tid & 63;
  const int wv = tid >> 6;              // wave = K-quarter owner
  const int l15 = lane & 15;
  const int lho = (lane >> 4) << 3;
  const int colbase = g * CPW;
  const int rowbase = p * 32;

  // persistent B fragments: 6 gate col-tiles + 1 mean tile (K-quarter per wave)
  short8 bfr[7][8];
  #pragma unroll
  for (int ct = 0; ct < 7; ++ct){
    const unsigned short* src = (ct < 6)
        ? (WHH + (size_t)((ct>>1)*H_ + colbase + (ct&1)*16 + l15)*H_)
        : (CM + (size_t)l15*H_);
    #pragma unroll
    for (int ks = 0; ks < 8; ++ks)
      bfr[ct][ks] = *(const short8*)(src + wv*256 + ks*32 + lho);
  }

  // gate-phase ownership: thread = (batch row b_, col-quad cq)
  const int b_ = tid & 31;              // 32 rows in this half
  const int cq = tid >> 5;              // 8 col-quads of 4
  const int c0 = colbase + cq*4;
  const int gb = rowbase + b_;          // global batch
  float gr[4],gz[4],gn[4],br_[4],bz_[4],bn_[4],hv[4];
  #pragma unroll
  for (int j = 0; j < 4; ++j){
    gr[j] = ghh[c0+j];   gz[j] = ghh[H_+c0+j];   gn[j] = ghh[2*H_+c0+j];
    br_[j]= bhh[c0+j];   bz_[j]= bhh[H_+c0+j];   bn_[j]= bhh[2*H_+c0+j];
    hv[j] = state[(size_t)gb*H_ + c0 + j];
  }

  // packed flag line for my half; wave 0 polls, one lane per flag (x2)
  const unsigned* myflag = FLAGS + p*32 + (lane & 31);
  unsigned* pubflag = FLAGS + p*32 + g;
  int cur = 0;

  for (int t = 0; t < S_; ++t){
    // ih gate inputs — issue before the poll so they ride under the wait
    const unsigned short* ihp = IH + ((size_t)t*B_ + gb)*G_;
    u16x4 ir  = ldg8(ihp + c0);
    u16x4 izv = ldg8(ihp + H_ + c0);
    u16x4 inv = ldg8(ihp + 2*H_ + c0);

    // flag barrier over my half's 32 producers — WAVE 0 ONLY polls
    if (wv == 0){
      for (;;){
        unsigned v = ldg4_coh_wait(myflag);
        if (__all((int)(v >= (unsigned)t))) break;
      }
    }
    __syncthreads();

    // A fragments: coherent read of my half's 32-row h panel, ks-major
    const unsigned short* hb = HB + cur*(B_*H_);
    short8 af[8][2];
    #pragma unroll
    for (int ks = 0; ks < 8; ++ks)
      #pragma unroll
      for (int rt = 0; rt < 2; ++rt)
        af[ks][rt] = ldg16_coh(hb + (size_t)(rowbase + rt*16 + l15)*H_ + wv*256 + ks*32 + lho);

    f32x4 acc[7][2];
    #pragma unroll
    for (int ct = 0; ct < 7; ++ct)
      #pragma unroll
      for (int rt = 0; rt < 2; ++rt)
        acc[ct][rt] = (f32x4){0.f,0.f,0.f,0.f};

    // counted-vmcnt overlap: MFMA on slice ks while later slices load
    #pragma unroll
    for (int ks = 0; ks < 8; ++ks){
      asm volatile("s_waitcnt vmcnt(%0)" :: "i"(14 - 2*ks) : "memory");
      __builtin_amdgcn_sched_barrier(0);
      #pragma unroll
      for (int rt = 0; rt < 2; ++rt)
        #pragma unroll
        for (int ct = 0; ct < 7; ++ct)
          acc[ct][rt] = __builtin_amdgcn_mfma_f32_16x16x32_bf16(af[ks][rt], bfr[ct][ks], acc[ct][rt], 0,0,0);
    }

    // K-partials -> LDS
    #pragma unroll
    for (int ct = 0; ct < 7; ++ct)
      #pragma unroll
      for (int rt = 0; rt < 2; ++rt)
        *(f32x4*)&PSUM[wv][ct*16 + l15][rt*16 + (lane>>4)*4] = acc[ct][rt];
    __syncthreads();

    // reduce 4 K-quarters; gates and h update
    float hhr[4]={0,0,0,0}, hhz[4]={0,0,0,0}, hhn[4]={0,0,0,0};
    float mrz = 0.f, mn = 0.f;
    #pragma unroll
    for (int w = 0; w < 4; ++w){
      #pragma unroll
      for (int j = 0; j < 4; ++j){
        hhr[j] += PSUM[w][cq*4 + j][b_];
        hhz[j] += PSUM[w][32 + cq*4 + j][b_];
        hhn[j] += PSUM[w][64 + cq*4 + j][b_];
      }
      mrz += PSUM[w][96][b_];
      mn  += PSUM[w][97][b_];
    }
    f32x4 ho;
    #pragma unroll
    for (int j = 0; j < 4; ++j){
      float R = sig_(bf16_to_f32(ir[j])  + gr[j]*(hhr[j]-mrz) + br_[j]);
      float Z = sig_(bf16_to_f32(izv[j]) + gz[j]*(hhz[j]-mrz) + bz_[j]);
      float N = tanh_(bf16_to_f32(inv[j]) + R*(gn[j]*(hhn[j]-mn) + bn_[j]));
      hv[j] = (1.0f - Z)*N + Z*hv[j];
      ho[j] = hv[j];
    }
    // out store FIRST so the single vmcnt(0) drain covers it (off poll path)
    *(f32x4*)(out + ((size_t)gb*S_ + t)*H_ + c0) = ho;
    u16x4 h16;
    #pragma unroll
    for (int j = 0; j < 4; ++j) h16[j] = f32_to_bf16(hv[j]);
    stg8_coh(HB + (cur^1)*(B_*H_) + (size_t)gb*H_ + c0, h16);

    // publish: h16 (+out) drained to coherence point -> raise flag
    asm volatile("s_waitcnt vmcnt(0)" ::: "memory");
    __syncthreads();
    if (tid == 0) stg4_coh(pubflag, (unsigned)(t+1));
    cur ^= 1;
  }
  #pragma unroll
  for (int j = 0; j < 4; ++j)
    out[(size_t)B_*S_*H_ + (size_t)gb*H_ + c0 + j] = hv[j];
}

// ---------------- host launcher ---------------------------------------------
extern "C" void kernel_launch(void* const* d_in, const int* in_sizes, int n_in,
                              void* d_out, int out_size, void* d_ws, size_t ws_size,
                              hipStream_t stream){
  (void)in_sizes; (void)n_in; (void)out_size; (void)ws_size;
  const float* x   = (const float*)d_in[0];
  const float* st  = (const float*)d_in[1];
  const float* wih = (const float*)d_in[2];
  const float* whh = (const float*)d_in[3];
  const float* bih = (const float*)d_in[4];
  const float* bhh = (const float*)d_in[5];
  const float* gih = (const float*)d_in[6];
  const float* ghh = (const float*)d_in[7];
  float* out = (float*)d_out;
  char* ws = (char*)d_ws;

  unsigned short* IH    = (unsigned short*)(ws);                   // 201,326,592
  unsigned short* X16   = (unsigned short*)(ws + 201326592ull);    //  33,554,432
  unsigned short* WIH16 = (unsigned short*)(ws + 234881024ull);    //   3,145,728
  unsigned short* WHH16 = (unsigned short*)(ws + 238026752ull);    //   6,291,456
  unsigned short* CM16  = (unsigned short*)(ws + 244318208ull);    //      32,768
  unsigned short* HB    = (unsigned short*)(ws + 244350976ull);    //     262,144
  unsigned*       FLAGS = (unsigned*)      (ws + 244613120ull);    //       4,096

  hipMemsetAsync(FLAGS, 0, 4096, stream);
  k_cvt4<<<2048, 256, 0, stream>>>(x,   X16,   4194304);
  k_cvt4<<<1024, 256, 0, stream>>>(wih, WIH16, 393216);
  k_cvt4<<<1024, 256, 0, stream>>>(whh, WHH16, 786432);
  k_cvt4<<<64,   256, 0, stream>>>(st,  HB,    16384);
  k_cmean<<<4,   256, 0, stream>>>(whh, CM16);
  k_gemm_ih<<<6144, 256, 0, stream>>>(X16, WIH16, IH);
  k_ln<<<32768, 256, 0, stream>>>(IH, gih, bih);
  k_gru<<<NWG, 256, 0, stream>>>(IH, WHH16, CM16, HB, ghh, bhh, st, out, FLAGS);
}